// Round 2
// baseline (2174.678 us; speedup 1.0000x reference)
//
#include <hip/hip_runtime.h>
#include <math.h>

// Problem constants
#define Bn 256
#define Tn 100
#define In 1024
#define Hn 2048
#define On 10
#define Kc (In + Hn)   // 3072 concatenated K

typedef short s8v  __attribute__((ext_vector_type(8)));   // 8 x bf16 (as raw shorts), 4 VGPRs
typedef unsigned short us8 __attribute__((ext_vector_type(8)));
typedef float f32x4 __attribute__((ext_vector_type(4)));

__device__ __forceinline__ unsigned short f2bf(float f) {
    unsigned int u = __float_as_uint(f);
    u += 0x7fffu + ((u >> 16) & 1u);   // round-to-nearest-even
    return (unsigned short)(u >> 16);
}

// ---- setup kernels -------------------------------------------------------

// x [B][T][I] fp32 -> bf16, 4 elems/thread
__global__ void conv_x_kernel(const float4* __restrict__ src, ushort4* __restrict__ dst) {
    int i = blockIdx.x * 256 + threadIdx.x;
    float4 v = src[i];
    ushort4 o;
    o.x = f2bf(v.x); o.y = f2bf(v.y); o.z = f2bf(v.z); o.w = f2bf(v.w);
    dst[i] = o;
}

// src [K][N=2048] fp32 -> dst[n][colOff + k] bf16  (builds B^T = [Win;W]^T rows)
__global__ void transpose_bf16_kernel(const float* __restrict__ src, unsigned short* __restrict__ dst,
                                      int N, int ld, int colOff) {
    __shared__ float tile[32][33];
    int k0 = blockIdx.x * 32;
    int n0 = blockIdx.y * 32;
    int c = threadIdx.x & 31;
    int r = threadIdx.x >> 5;            // 0..7
    #pragma unroll
    for (int i = 0; i < 32; i += 8)
        tile[r + i][c] = src[(size_t)(k0 + r + i) * N + n0 + c];
    __syncthreads();
    #pragma unroll
    for (int i = 0; i < 32; i += 8)
        dst[(size_t)(n0 + r + i) * ld + colOff + k0 + c] = f2bf(tile[c][r + i]);
}

// h0 -> h_all slot 0 (bf16); lin_w [10][2048] -> padded bf16 [16][2048] (rows 10..15 = 0)
__global__ void small_conv_kernel(const float* __restrict__ h0, const float* __restrict__ lin_w,
                                  unsigned short* __restrict__ h_all0, unsigned short* __restrict__ lwb) {
    int idx = blockIdx.x * 256 + threadIdx.x;
    if (idx < Bn * Hn) {
        h_all0[idx] = f2bf(h0[idx]);
    } else {
        int j = idx - Bn * Hn;           // < 16*2048
        int o = j >> 11;
        int k = j & 2047;
        lwb[j] = (o < On) ? f2bf(lin_w[o * Hn + k]) : (unsigned short)0;
    }
}

// ---- one scan step -------------------------------------------------------
// 256 blocks x 256 thr. Block (m_tile 0..3 [64 rows], n_tile 0..63 [32 cols]).
// n_tile XCD-pinned via blockIdx%8 for B^T L2 locality. 4 waves split K=3072
// (768 each); per wave 4 m-frags x 2 n-frags of 16x16x32 bf16 MFMA. Cross-wave
// reduce in LDS, tanh, write bf16 h_{t+1}. One launch per t: stream ordering
// provides the inter-step barrier (no cooperative launch — it silently failed
// in round 1, leaving h_all poisoned and y == bias).
__global__ __launch_bounds__(256, 1)
void step_kernel(const unsigned short* __restrict__ xb,
                 const unsigned short* __restrict__ BTm,
                 unsigned short* __restrict__ h_all,
                 int t) {
    const int g = blockIdx.x;
    const int m0 = ((g >> 3) & 3) * 64;                 // 4 m-tiles
    const int n0 = ((g & 7) * 8 + (g >> 5)) * 32;       // 64 n-tiles, XCD-pinned
    const int w = threadIdx.x >> 6;
    const int lane = threadIdx.x & 63;
    const int quad = lane >> 4;
    const int lr = lane & 15;

    __shared__ float red[4][64][33];                    // +1 pad: breaks 4-way bank conflict

    const unsigned short* bp0 = BTm + (size_t)(n0 + lr) * Kc;
    const unsigned short* bp1 = BTm + (size_t)(n0 + 16 + lr) * Kc;

    const int kbase = w * 768;                          // wave K-split
    const size_t xrow = (size_t)Tn * In;                // x row stride (102400)

    f32x4 acc[4][2];
    #pragma unroll
    for (int mi = 0; mi < 4; ++mi)
        #pragma unroll
        for (int ni = 0; ni < 2; ++ni)
            acc[mi][ni] = (f32x4){0.f, 0.f, 0.f, 0.f};

    const unsigned short* hprev = h_all + (size_t)t * (Bn * Hn);
    const unsigned short* xt = xb + (size_t)t * In;

    #pragma unroll
    for (int kk = 0; kk < 24; ++kk) {
        const int k0 = kbase + kk * 32;
        const int kq = k0 + quad * 8;
        const unsigned short* ab;
        size_t rstr;
        if (k0 < In) { ab = xt + kq; rstr = xrow; }           // x region (wave-uniform branch)
        else         { ab = hprev + (kq - In); rstr = Hn; }   // h region
        const unsigned short* arow = ab + (size_t)(m0 + lr) * rstr;
        s8v a0 = *(const s8v*)(arow);
        s8v a1 = *(const s8v*)(arow + 16 * rstr);
        s8v a2 = *(const s8v*)(arow + 32 * rstr);
        s8v a3 = *(const s8v*)(arow + 48 * rstr);
        s8v b0 = *(const s8v*)(bp0 + kq);
        s8v b1 = *(const s8v*)(bp1 + kq);
        acc[0][0] = __builtin_amdgcn_mfma_f32_16x16x32_bf16(a0, b0, acc[0][0], 0, 0, 0);
        acc[1][0] = __builtin_amdgcn_mfma_f32_16x16x32_bf16(a1, b0, acc[1][0], 0, 0, 0);
        acc[2][0] = __builtin_amdgcn_mfma_f32_16x16x32_bf16(a2, b0, acc[2][0], 0, 0, 0);
        acc[3][0] = __builtin_amdgcn_mfma_f32_16x16x32_bf16(a3, b0, acc[3][0], 0, 0, 0);
        acc[0][1] = __builtin_amdgcn_mfma_f32_16x16x32_bf16(a0, b1, acc[0][1], 0, 0, 0);
        acc[1][1] = __builtin_amdgcn_mfma_f32_16x16x32_bf16(a1, b1, acc[1][1], 0, 0, 0);
        acc[2][1] = __builtin_amdgcn_mfma_f32_16x16x32_bf16(a2, b1, acc[2][1], 0, 0, 0);
        acc[3][1] = __builtin_amdgcn_mfma_f32_16x16x32_bf16(a3, b1, acc[3][1], 0, 0, 0);
    }

    // C/D layout: row = quad*4 + reg, col = lane&15  [verified m89/m91]
    #pragma unroll
    for (int mi = 0; mi < 4; ++mi)
        #pragma unroll
        for (int ni = 0; ni < 2; ++ni)
            #pragma unroll
            for (int rr = 0; rr < 4; ++rr)
                red[w][mi * 16 + quad * 4 + rr][ni * 16 + lr] = acc[mi][ni][rr];
    __syncthreads();

    {   // 256 threads reduce 4 partials for 2048 outputs (8 each), tanh, store bf16
        int j = threadIdx.x << 3;
        int row = j >> 5;
        int c0 = j & 31;
        us8 o8;
        #pragma unroll
        for (int c = 0; c < 8; ++c) {
            float s = red[0][row][c0 + c] + red[1][row][c0 + c]
                    + red[2][row][c0 + c] + red[3][row][c0 + c];
            o8[c] = f2bf(tanhf(s));
        }
        *(us8*)(h_all + (size_t)(t + 1) * (Bn * Hn) + (size_t)(m0 + row) * Hn + n0 + c0) = o8;
    }
}

// ---- output projection ---------------------------------------------------
// y[b][t][o] = h_all[t+1][b][:] . lin_w[o][:] + lin_b[o]. One 16-row wave per 16 (t,b) rows.
__global__ __launch_bounds__(256)
void gemm2_kernel(const unsigned short* __restrict__ h_all, const unsigned short* __restrict__ lwb,
                  const float* __restrict__ lb, float* __restrict__ y) {
    int gw = blockIdx.x * 4 + (threadIdx.x >> 6);       // 0..1599
    int lane = threadIdx.x & 63, quad = lane >> 4, lr = lane & 15;
    int m0 = gw * 16;
    int t = m0 >> 8;
    int b0 = m0 & 255;
    const unsigned short* ah = h_all + ((size_t)(t + 1) * Bn + b0 + lr) * Hn + quad * 8;
    const unsigned short* bh = lwb + (size_t)lr * Hn + quad * 8;
    f32x4 acc0 = {0.f, 0.f, 0.f, 0.f}, acc1 = {0.f, 0.f, 0.f, 0.f};
    #pragma unroll
    for (int k0 = 0; k0 < Hn; k0 += 64) {
        s8v a0 = *(const s8v*)(ah + k0);
        s8v b0 = *(const s8v*)(bh + k0);
        acc0 = __builtin_amdgcn_mfma_f32_16x16x32_bf16(a0, b0, acc0, 0, 0, 0);
        s8v a1 = *(const s8v*)(ah + k0 + 32);
        s8v b1 = *(const s8v*)(bh + k0 + 32);
        acc1 = __builtin_amdgcn_mfma_f32_16x16x32_bf16(a1, b1, acc1, 0, 0, 0);
    }
    acc0 = acc0 + acc1;
    if (lr < On) {
        float bias = lb[lr];
        #pragma unroll
        for (int rr = 0; rr < 4; ++rr) {
            int b = b0 + quad * 4 + rr;
            y[(size_t)b * (Tn * On) + t * On + lr] = acc0[rr] + bias;
        }
    }
}

// ---- host ----------------------------------------------------------------

extern "C" void kernel_launch(void* const* d_in, const int* in_sizes, int n_in,
                              void* d_out, int out_size, void* d_ws, size_t ws_size,
                              hipStream_t stream) {
    const float* x   = (const float*)d_in[0];
    const float* h0  = (const float*)d_in[1];
    const float* Win = (const float*)d_in[2];
    const float* W   = (const float*)d_in[3];
    const float* lw  = (const float*)d_in[4];
    const float* lb  = (const float*)d_in[5];
    float* y = (float*)d_out;

    // ws layout (bf16 elems): ~171 MB total
    unsigned short* ws    = (unsigned short*)d_ws;
    unsigned short* xb    = ws;                                  // 26,214,400 elems
    unsigned short* BTm   = xb + (size_t)Bn * Tn * In;           //  6,291,456 elems [2048][3072]
    unsigned short* h_all = BTm + (size_t)Hn * Kc;               // 52,953,088 elems [(T+1)][B][H]
    unsigned short* lwb   = h_all + (size_t)(Tn + 1) * Bn * Hn;  //     32,768 elems [16][2048]

    conv_x_kernel<<<25600, 256, 0, stream>>>((const float4*)x, (ushort4*)xb);
    transpose_bf16_kernel<<<dim3(32, 64), 256, 0, stream>>>(Win, BTm, Hn, Kc, 0);
    transpose_bf16_kernel<<<dim3(64, 64), 256, 0, stream>>>(W, BTm, Hn, Kc, In);
    small_conv_kernel<<<2176, 256, 0, stream>>>(h0, lw, h_all, lwb);

    for (int t = 0; t < Tn; ++t)
        step_kernel<<<256, 256, 0, stream>>>(xb, BTm, h_all, t);

    gemm2_kernel<<<400, 256, 0, stream>>>(h_all, lwb, lb, y);
}